// Round 2
// baseline (234.751 us; speedup 1.0000x reference)
//
#include <hip/hip_runtime.h>
#include <stdint.h>

#define NB 8
#define NHEAD 12
#define SEQ 1024
#define CDIM 768
#define HDIM 64

// (1/sqrt(64)) * log2(e)
#define SCALE_L2E 0.1803368801111244f
#define L2E 1.4426950408889634f

typedef __attribute__((ext_vector_type(8))) short bf16x8;
typedef __attribute__((ext_vector_type(4))) short bf16x4;
typedef __attribute__((ext_vector_type(4))) float f32x4;
typedef __attribute__((ext_vector_type(4))) unsigned short us4;

__device__ __forceinline__ void gload_lds16(const void* g, void* l) {
  __builtin_amdgcn_global_load_lds((const __attribute__((address_space(1))) void*)g,
                                   (__attribute__((address_space(3))) void*)l,
                                   16, 0, 0);
}

__device__ __forceinline__ unsigned short f2bf(float f) {
  __bf16 h = (__bf16)f;
  return __builtin_bit_cast(unsigned short, h);
}

__device__ __forceinline__ f32x4 mfma16(bf16x8 a, bf16x8 b, f32x4 c) {
  return __builtin_amdgcn_mfma_f32_16x16x32_bf16(a, b, c, 0, 0, 0);
}

// ---------------- conversion kernels ----------------

__global__ void cvt_x_kernel(const float* __restrict__ in,
                             unsigned short* __restrict__ out, int n8) {
  int i = blockIdx.x * blockDim.x + threadIdx.x;
  if (i >= n8) return;
  const float4* p = (const float4*)in;
  float4 a = p[2 * i], b = p[2 * i + 1];
  union { bf16x8 v; unsigned short h[8]; } u;
  u.h[0] = f2bf(a.x); u.h[1] = f2bf(a.y); u.h[2] = f2bf(a.z); u.h[3] = f2bf(a.w);
  u.h[4] = f2bf(b.x); u.h[5] = f2bf(b.y); u.h[6] = f2bf(b.z); u.h[7] = f2bf(b.w);
  ((bf16x8*)out)[i] = u.v;
}

// in [K][N] f32  ->  out [N][K] bf16   (grid: (N/32, K/32), 256 thr)
__global__ void tconv_kernel(const float* __restrict__ in,
                             unsigned short* __restrict__ out, int K, int N) {
  __shared__ float tile[32][33];
  int tx = threadIdx.x & 31, ty = threadIdx.x >> 5;
  int n0 = blockIdx.x * 32, k0 = blockIdx.y * 32;
#pragma unroll
  for (int i = 0; i < 4; i++)
    tile[ty + 8 * i][tx] = in[(size_t)(k0 + ty + 8 * i) * N + n0 + tx];
  __syncthreads();
#pragma unroll
  for (int i = 0; i < 4; i++)
    out[(size_t)(n0 + ty + 8 * i) * K + k0 + tx] = f2bf(tile[tx][ty + 8 * i]);
}

// ---------------- GEMM:  C[M][N] = A[M][K] * Bt[N][K]^T + bias ----------------
// Double-buffered LDS, one barrier per K-step (T3 minimum-2-phase):
//   stage(next) -> compute(cur) -> __syncthreads() (drain lands after MFMAs)
// EPI 0: scatter to Q [B,H,N,D], K [B,H,N,D], V^T [B,H,D,N]  (bf16)
// EPI 1: f32 out [M][N]
template <int EPI>
__global__ __launch_bounds__(256, 4)
void gemm_bt_kernel(const unsigned short* __restrict__ A,
                    const unsigned short* __restrict__ Bt,
                    const float* __restrict__ bias,
                    unsigned short* __restrict__ q_out,
                    unsigned short* __restrict__ k_out,
                    unsigned short* __restrict__ v_out,
                    float* __restrict__ f_out,
                    int M, int N, int K) {
  __shared__ __align__(16) unsigned short As[2][128 * 32];
  __shared__ __align__(16) unsigned short Bs[2][128 * 32];
  const int t = threadIdx.x;
  const int w = t >> 6, l = t & 63;
  const int g = l >> 4, lr = l & 15;
  const int wr = w >> 1, wc = w & 1;
  const int nTN = N >> 7;
  const int bm = blockIdx.x / nTN, bn = blockIdx.x % nTN;
  const int m0 = bm << 7, n0 = bn << 7;

  f32x4 acc[4][4];
#pragma unroll
  for (int i = 0; i < 4; i++)
#pragma unroll
    for (int j = 0; j < 4; j++) acc[i][j] = f32x4{0.f, 0.f, 0.f, 0.f};

  // staging: thread stages 16B chunks t and t+256 of each tile.
  // chunk c: row = c>>2, slot = c&3 ; source k-chunk = slot ^ ((row>>1)&3)
  const int r0c = t >> 2, s0c = t & 3;
  const int r1c = (t + 256) >> 2;
  const int ks0 = s0c ^ ((r0c >> 1) & 3);
  const int ks1 = s0c ^ ((r1c >> 1) & 3);
  const unsigned short* a0 = A + (size_t)(m0 + r0c) * K + ks0 * 8;
  const unsigned short* a1 = A + (size_t)(m0 + r1c) * K + ks1 * 8;
  const unsigned short* b0 = Bt + (size_t)(n0 + r0c) * K + ks0 * 8;
  const unsigned short* b1 = Bt + (size_t)(n0 + r1c) * K + ks1 * 8;

  const int swr = (lr >> 1) & 3;  // read-side swizzle (matches staging)

  auto stage = [&](int buf, int kk) {
    gload_lds16(a0 + kk, As[buf] + t * 8);
    gload_lds16(a1 + kk, As[buf] + (t + 256) * 8);
    gload_lds16(b0 + kk, Bs[buf] + t * 8);
    gload_lds16(b1 + kk, Bs[buf] + (t + 256) * 8);
  };

  stage(0, 0);
  __syncthreads();  // prologue drain (exposed once)
  int cur = 0;
  for (int kk = 0; kk < K; kk += 32) {
    if (kk + 32 < K) stage(cur ^ 1, kk + 32);  // prefetch next tile
    // compute current tile
    bf16x8 af[4];
#pragma unroll
    for (int i = 0; i < 4; i++) {
      int row = wr * 64 + i * 16 + lr;
      af[i] = *(const bf16x8*)(As[cur] + row * 32 + ((g ^ swr) << 3));
    }
#pragma unroll
    for (int j = 0; j < 4; j++) {
      int row = wc * 64 + j * 16 + lr;
      bf16x8 bfr = *(const bf16x8*)(Bs[cur] + row * 32 + ((g ^ swr) << 3));
#pragma unroll
      for (int i = 0; i < 4; i++) acc[i][j] = mfma16(af[i], bfr, acc[i][j]);
    }
    __syncthreads();  // single barrier: drains prefetch AFTER the MFMAs
    cur ^= 1;
  }

  float bv[4];
#pragma unroll
  for (int j = 0; j < 4; j++) bv[j] = bias[n0 + wc * 64 + j * 16 + lr];

  if (EPI == 1) {
#pragma unroll
    for (int i = 0; i < 4; i++) {
      int mrow = m0 + wr * 64 + i * 16 + 4 * g;
#pragma unroll
      for (int j = 0; j < 4; j++) {
        int n = n0 + wc * 64 + j * 16 + lr;
#pragma unroll
        for (int r = 0; r < 4; r++)
          f_out[(size_t)(mrow + r) * N + n] = acc[i][j][r] + bv[j];
      }
    }
  } else {
    const int which = n0 / CDIM;      // uniform per block (128 | 768)
    const int bb = m0 / SEQ;          // uniform per block (128 | 1024)
    const int tok0 = (m0 % SEQ) + wr * 64;
#pragma unroll
    for (int j = 0; j < 4; j++) {
      int ncol = (n0 % CDIM) + wc * 64 + j * 16;
      int hh = ncol / 64;             // uniform per fragment
      int d = (ncol % 64) + lr;
#pragma unroll
      for (int i = 0; i < 4; i++) {
        int tokb = tok0 + i * 16 + 4 * g;
        if (which == 2) {
          us4 pk;
#pragma unroll
          for (int r = 0; r < 4; r++) pk[r] = f2bf(acc[i][j][r] + bv[j]);
          *(us4*)(v_out + ((size_t)(bb * NHEAD + hh) * 64 + d) * SEQ + tokb) = pk;
        } else {
          unsigned short* dst = (which == 0) ? q_out : k_out;
#pragma unroll
          for (int r = 0; r < 4; r++)
            dst[((size_t)(bb * NHEAD + hh) * SEQ + tokb + r) * 64 + d] =
                f2bf(acc[i][j][r] + bv[j]);
        }
      }
    }
  }
}

// ---------------- fused flash attention ----------------
// grid: B*H*8 blocks; block = (b,h, 128-query tile); 4 waves.
// S^T = K*Q^T (swapped) so softmax stats are lane-local per query col.
__global__ __launch_bounds__(256, 3)
void attn_kernel(const unsigned short* __restrict__ Qb,
                 const unsigned short* __restrict__ Kb,
                 const unsigned short* __restrict__ Vt,
                 const float* __restrict__ mask,
                 unsigned short* __restrict__ Ob) {
  __shared__ __align__(16) unsigned short Qs[128 * 64];
  __shared__ __align__(16) unsigned short Ks[128 * 64];
  __shared__ __align__(16) unsigned short Vs[64 * 128];
  __shared__ __align__(16) float smask[128];

  const int bid = blockIdx.x;
  const int qt = bid & 7;
  const int h = (bid >> 3) % NHEAD;
  const int b = bid / (8 * NHEAD);
  const int t = threadIdx.x, w = t >> 6, l = t & 63;
  const int g = l >> 4, lr = l & 15;

  const unsigned short* Qg = Qb + (((size_t)b * NHEAD + h) * SEQ + qt * 128) * 64;
  const unsigned short* Kg = Kb + ((size_t)b * NHEAD + h) * SEQ * 64;
  const unsigned short* Vg = Vt + ((size_t)b * NHEAD + h) * 64 * SEQ;
  const float* mg = mask + (size_t)b * SEQ;

  // number of non-fully-masked key blocks (padding is a tail; lengths >= 512)
  int nkb = 8;
#pragma unroll
  for (int kb = 7; kb >= 4; kb--)
    if (mg[kb * 128] < -1e8f) nkb = kb;

  // stage Q (XOR-swizzled rows: slot = kchunk ^ (row&7))
#pragma unroll
  for (int i = 0; i < 4; i++) {
    int c = t + 256 * i;
    int row = c >> 3, sl = c & 7;
    gload_lds16(Qg + row * 64 + ((sl ^ (row & 7)) << 3), Qs + c * 8);
  }
  __syncthreads();

  // hoist Q fragments (B-operand: col = query = lr, k = d)
  bf16x8 qfr[2][2];
#pragma unroll
  for (int qi = 0; qi < 2; qi++)
#pragma unroll
    for (int ks = 0; ks < 2; ks++) {
      int row = w * 32 + qi * 16 + lr;
      qfr[qi][ks] =
          *(const bf16x8*)(Qs + row * 64 + (((ks * 4 + g) ^ (lr & 7)) << 3));
    }

  float m_run[2] = {-1e30f, -1e30f};
  float l_run[2] = {0.f, 0.f};
  f32x4 oacc[2][4];
#pragma unroll
  for (int qi = 0; qi < 2; qi++)
#pragma unroll
    for (int df = 0; df < 4; df++) oacc[qi][df] = f32x4{0.f, 0.f, 0.f, 0.f};

  for (int kb = 0; kb < nkb; kb++) {
    __syncthreads();  // previous compute done before overwrite
    // stage K tile [128 keys][64 d], swizzled
#pragma unroll
    for (int i = 0; i < 4; i++) {
      int c = t + 256 * i;
      int row = c >> 3, sl = c & 7;
      gload_lds16(Kg + (size_t)(kb * 128 + row) * 64 + ((sl ^ (row & 7)) << 3),
                  Ks + c * 8);
    }
    // stage V^T tile [64 d][128 keys], swizzled on low 3 slot bits
#pragma unroll
    for (int i = 0; i < 4; i++) {
      int c = t + 256 * i;
      int row = c >> 4, sl = c & 15;
      gload_lds16(Vg + (size_t)row * SEQ + kb * 128 + ((sl ^ (row & 7)) << 3),
                  Vs + c * 8);
    }
    if (t < 128) smask[t] = mg[kb * 128 + t] * L2E;
    __syncthreads();

    // S^T = K * Q^T : rows = keys(128), cols = this wave's 32 queries
    f32x4 sacc[8][2];
#pragma unroll
    for (int kf = 0; kf < 8; kf++)
#pragma unroll
      for (int qi = 0; qi < 2; qi++) sacc[kf][qi] = f32x4{0.f, 0.f, 0.f, 0.f};
#pragma unroll
    for (int ks = 0; ks < 2; ks++)
#pragma unroll
      for (int kf = 0; kf < 8; kf++) {
        int row = kf * 16 + lr;
        bf16x8 a =
            *(const bf16x8*)(Ks + row * 64 + (((ks * 4 + g) ^ (lr & 7)) << 3));
        sacc[kf][0] = mfma16(a, qfr[0][ks], sacc[kf][0]);
        sacc[kf][1] = mfma16(a, qfr[1][ks], sacc[kf][1]);
      }

    // logits in log2 domain + additive mask (key = kf*16 + 4g + r)
#pragma unroll
    for (int kf = 0; kf < 8; kf++) {
      f32x4 mv = *(const f32x4*)(smask + kf * 16 + 4 * g);
#pragma unroll
      for (int qi = 0; qi < 2; qi++)
#pragma unroll
        for (int r = 0; r < 4; r++)
          sacc[kf][qi][r] = sacc[kf][qi][r] * SCALE_L2E + mv[r];
    }

    // online softmax (per query column lr; reduce over g-groups)
    float scal[2];
#pragma unroll
    for (int qi = 0; qi < 2; qi++) {
      float bm = -1e30f;
#pragma unroll
      for (int kf = 0; kf < 8; kf++)
#pragma unroll
        for (int r = 0; r < 4; r++) bm = fmaxf(bm, sacc[kf][qi][r]);
      bm = fmaxf(bm, __shfl_xor(bm, 16));
      bm = fmaxf(bm, __shfl_xor(bm, 32));
      float mnew = fmaxf(m_run[qi], bm);
      scal[qi] = __builtin_amdgcn_exp2f(m_run[qi] - mnew);
      m_run[qi] = mnew;
      float bs = 0.f;
#pragma unroll
      for (int kf = 0; kf < 8; kf++)
#pragma unroll
        for (int r = 0; r < 4; r++) {
          float p = __builtin_amdgcn_exp2f(sacc[kf][qi][r] - mnew);
          sacc[kf][qi][r] = p;
          bs += p;
        }
      bs += __shfl_xor(bs, 16);
      bs += __shfl_xor(bs, 32);
      l_run[qi] = l_run[qi] * scal[qi] + bs;
    }

    // rescale O accumulators (scale indexed by D-row = 4g+r, gathered by shfl)
#pragma unroll
    for (int qi = 0; qi < 2; qi++)
#pragma unroll
      for (int r = 0; r < 4; r++) {
        float sc = __shfl(scal[qi], 4 * g + r);
#pragma unroll
        for (int df = 0; df < 4; df++) oacc[qi][df][r] *= sc;
      }

    // PV: P stays in registers; both operands use the same k-slot bijection
    // kappa(g,j) = 32kc + 16*(j>>2) + 4g + (j&3)
#pragma unroll
    for (int kc = 0; kc < 4; kc++) {
      bf16x8 pa[2];
#pragma unroll
      for (int qi = 0; qi < 2; qi++) {
        union { bf16x8 v; unsigned short hh[8]; } u;
#pragma unroll
        for (int r = 0; r < 4; r++) {
          u.hh[r] = f2bf(sacc[2 * kc][qi][r]);
          u.hh[4 + r] = f2bf(sacc[2 * kc + 1][qi][r]);
        }
        pa[qi] = u.v;
      }
      const int sw = (lr & 7) << 4;
#pragma unroll
      for (int df = 0; df < 4; df++) {
        const char* vp = (const char*)(Vs + (df * 16 + lr) * 128);
        bf16x4 lo = *(const bf16x4*)(vp + ((kc * 64 + 8 * g) ^ sw));
        bf16x4 hi = *(const bf16x4*)(vp + ((kc * 64 + 32 + 8 * g) ^ sw));
        bf16x8 vb = __builtin_shufflevector(lo, hi, 0, 1, 2, 3, 4, 5, 6, 7);
        oacc[0][df] = mfma16(pa[0], vb, oacc[0][df]);
        oacc[1][df] = mfma16(pa[1], vb, oacc[1][df]);
      }
    }
  }

  // epilogue: divide by l, write O as bf16 [B, tok, h*64 + d]
#pragma unroll
  for (int qi = 0; qi < 2; qi++) {
    float linv = 1.f / l_run[qi];
#pragma unroll
    for (int r = 0; r < 4; r++) {
      float li = __shfl(linv, 4 * g + r);
      int tok = qt * 128 + w * 32 + qi * 16 + 4 * g + r;
#pragma unroll
      for (int df = 0; df < 4; df++) {
        float val = oacc[qi][df][r] * li;
        Ob[((size_t)b * SEQ + tok) * CDIM + h * 64 + df * 16 + lr] = f2bf(val);
      }
    }
  }
}

// ---------------- launcher ----------------
extern "C" void kernel_launch(void* const* d_in, const int* in_sizes, int n_in,
                              void* d_out, int out_size, void* d_ws,
                              size_t ws_size, hipStream_t stream) {
  const float* x = (const float*)d_in[0];
  const float* mask = (const float*)d_in[1];
  const float* Wqkv = (const float*)d_in[2];
  const float* bqkv = (const float*)d_in[3];
  const float* Wproj = (const float*)d_in[4];
  const float* bproj = (const float*)d_in[5];
  float* out = (float*)d_out;

  char* ws = (char*)d_ws;
  size_t off = 0;
  auto take = [&](size_t bytes) {
    char* p = ws + off;
    off += (bytes + 255) & ~(size_t)255;
    return p;
  };
  unsigned short* xb = (unsigned short*)take((size_t)NB * SEQ * CDIM * 2);
  unsigned short* wqt = (unsigned short*)take((size_t)3 * CDIM * CDIM * 2);
  unsigned short* wpt = (unsigned short*)take((size_t)CDIM * CDIM * 2);
  unsigned short* Qb = (unsigned short*)take((size_t)NB * NHEAD * SEQ * 64 * 2);
  unsigned short* Kbf = (unsigned short*)take((size_t)NB * NHEAD * SEQ * 64 * 2);
  unsigned short* Vt = (unsigned short*)take((size_t)NB * NHEAD * SEQ * 64 * 2);
  unsigned short* Ob = (unsigned short*)take((size_t)NB * SEQ * CDIM * 2);

  int n8 = NB * SEQ * CDIM / 8;
  cvt_x_kernel<<<(n8 + 255) / 256, 256, 0, stream>>>(x, xb, n8);
  tconv_kernel<<<dim3(3 * CDIM / 32, CDIM / 32), 256, 0, stream>>>(Wqkv, wqt,
                                                                   CDIM, 3 * CDIM);
  tconv_kernel<<<dim3(CDIM / 32, CDIM / 32), 256, 0, stream>>>(Wproj, wpt, CDIM,
                                                               CDIM);
  gemm_bt_kernel<0><<<(NB * SEQ / 128) * (3 * CDIM / 128), 256, 0, stream>>>(
      xb, wqt, bqkv, Qb, Kbf, Vt, nullptr, NB * SEQ, 3 * CDIM, CDIM);
  attn_kernel<<<NB * NHEAD * 8, 256, 0, stream>>>(Qb, Kbf, Vt, mask, Ob);
  gemm_bt_kernel<1><<<(NB * SEQ / 128) * (CDIM / 128), 256, 0, stream>>>(
      Ob, wpt, bproj, nullptr, nullptr, nullptr, out, NB * SEQ, CDIM, CDIM);
}

// Round 3
// 211.956 us; speedup vs baseline: 1.1075x; 1.1075x over previous
//
#include <hip/hip_runtime.h>
#include <stdint.h>

#define NB 8
#define NHEAD 12
#define SEQ 1024
#define CDIM 768
#define HDIM 64

// (1/sqrt(64)) * log2(e)
#define SCALE_L2E 0.1803368801111244f
#define L2E 1.4426950408889634f

typedef __attribute__((ext_vector_type(8))) short bf16x8;
typedef __attribute__((ext_vector_type(4))) short bf16x4;
typedef __attribute__((ext_vector_type(4))) float f32x4;
typedef __attribute__((ext_vector_type(4))) unsigned short us4;

__device__ __forceinline__ void gload_lds16(const void* g, void* l) {
  __builtin_amdgcn_global_load_lds((const __attribute__((address_space(1))) void*)g,
                                   (__attribute__((address_space(3))) void*)l,
                                   16, 0, 0);
}

__device__ __forceinline__ unsigned short f2bf(float f) {
  __bf16 h = (__bf16)f;
  return __builtin_bit_cast(unsigned short, h);
}

__device__ __forceinline__ f32x4 mfma16(bf16x8 a, bf16x8 b, f32x4 c) {
  return __builtin_amdgcn_mfma_f32_16x16x32_bf16(a, b, c, 0, 0, 0);
}

// ---------------- conversion kernels ----------------

__global__ void cvt_x_kernel(const float* __restrict__ in,
                             unsigned short* __restrict__ out, int n8) {
  int i = blockIdx.x * blockDim.x + threadIdx.x;
  if (i >= n8) return;
  const float4* p = (const float4*)in;
  float4 a = p[2 * i], b = p[2 * i + 1];
  union { bf16x8 v; unsigned short h[8]; } u;
  u.h[0] = f2bf(a.x); u.h[1] = f2bf(a.y); u.h[2] = f2bf(a.z); u.h[3] = f2bf(a.w);
  u.h[4] = f2bf(b.x); u.h[5] = f2bf(b.y); u.h[6] = f2bf(b.z); u.h[7] = f2bf(b.w);
  ((bf16x8*)out)[i] = u.v;
}

// in [K][N] f32  ->  out [N][K] bf16   (grid: (N/32, K/32), 256 thr)
__global__ void tconv_kernel(const float* __restrict__ in,
                             unsigned short* __restrict__ out, int K, int N) {
  __shared__ float tile[32][33];
  int tx = threadIdx.x & 31, ty = threadIdx.x >> 5;
  int n0 = blockIdx.x * 32, k0 = blockIdx.y * 32;
#pragma unroll
  for (int i = 0; i < 4; i++)
    tile[ty + 8 * i][tx] = in[(size_t)(k0 + ty + 8 * i) * N + n0 + tx];
  __syncthreads();
#pragma unroll
  for (int i = 0; i < 4; i++)
    out[(size_t)(n0 + ty + 8 * i) * K + k0 + tx] = f2bf(tile[tx][ty + 8 * i]);
}

// ---------------- GEMM:  C[M][N] = A[M][K] * Bt[N][K]^T + bias ----------------
// R1-proven single-buffer 2-barrier structure; occupancy fix: 4 blocks/CU.
// EPI 0: scatter to Q [B,H,N,D], K [B,H,N,D], V^T [B,H,D,N]  (bf16)
// EPI 1: f32 out [M][N]
template <int EPI>
__global__ __launch_bounds__(256, 4)
void gemm_bt_kernel(const unsigned short* __restrict__ A,
                    const unsigned short* __restrict__ Bt,
                    const float* __restrict__ bias,
                    unsigned short* __restrict__ q_out,
                    unsigned short* __restrict__ k_out,
                    unsigned short* __restrict__ v_out,
                    float* __restrict__ f_out,
                    int M, int N, int K) {
  __shared__ __align__(16) unsigned short As[128 * 32];
  __shared__ __align__(16) unsigned short Bs[128 * 32];
  const int t = threadIdx.x;
  const int w = t >> 6, l = t & 63;
  const int g = l >> 4, lr = l & 15;
  const int wr = w >> 1, wc = w & 1;
  const int nTN = N >> 7;
  const int bm = blockIdx.x / nTN, bn = blockIdx.x % nTN;
  const int m0 = bm << 7, n0 = bn << 7;

  f32x4 acc[4][4];
#pragma unroll
  for (int i = 0; i < 4; i++)
#pragma unroll
    for (int j = 0; j < 4; j++) acc[i][j] = f32x4{0.f, 0.f, 0.f, 0.f};

  // staging: thread stages 16B chunks t and t+256 of each tile.
  // chunk c: row = c>>2, slot = c&3 ; source k-chunk = slot ^ ((row>>1)&3)
  const int r0c = t >> 2, s0c = t & 3;
  const int r1c = (t + 256) >> 2;
  const int ks0 = s0c ^ ((r0c >> 1) & 3);
  const int ks1 = s0c ^ ((r1c >> 1) & 3);
  const unsigned short* a0 = A + (size_t)(m0 + r0c) * K + ks0 * 8;
  const unsigned short* a1 = A + (size_t)(m0 + r1c) * K + ks1 * 8;
  const unsigned short* b0 = Bt + (size_t)(n0 + r0c) * K + ks0 * 8;
  const unsigned short* b1 = Bt + (size_t)(n0 + r1c) * K + ks1 * 8;
  unsigned short* lA0 = As + t * 8;
  unsigned short* lA1 = As + (t + 256) * 8;
  unsigned short* lB0 = Bs + t * 8;
  unsigned short* lB1 = Bs + (t + 256) * 8;

  const int swr = (lr >> 1) & 3;  // read-side swizzle (matches staging)

  for (int kk = 0; kk < K; kk += 32) {
    gload_lds16(a0 + kk, lA0);
    gload_lds16(a1 + kk, lA1);
    gload_lds16(b0 + kk, lB0);
    gload_lds16(b1 + kk, lB1);
    __syncthreads();  // drains vmcnt before barrier -> staged data visible
    bf16x8 af[4];
#pragma unroll
    for (int i = 0; i < 4; i++) {
      int row = wr * 64 + i * 16 + lr;
      af[i] = *(const bf16x8*)(As + row * 32 + ((g ^ swr) << 3));
    }
#pragma unroll
    for (int j = 0; j < 4; j++) {
      int row = wc * 64 + j * 16 + lr;
      bf16x8 bfr = *(const bf16x8*)(Bs + row * 32 + ((g ^ swr) << 3));
#pragma unroll
      for (int i = 0; i < 4; i++) acc[i][j] = mfma16(af[i], bfr, acc[i][j]);
    }
    __syncthreads();  // compute done before next overwrite
  }

  float bv[4];
#pragma unroll
  for (int j = 0; j < 4; j++) bv[j] = bias[n0 + wc * 64 + j * 16 + lr];

  if (EPI == 1) {
#pragma unroll
    for (int i = 0; i < 4; i++) {
      int mrow = m0 + wr * 64 + i * 16 + 4 * g;
#pragma unroll
      for (int j = 0; j < 4; j++) {
        int n = n0 + wc * 64 + j * 16 + lr;
#pragma unroll
        for (int r = 0; r < 4; r++)
          f_out[(size_t)(mrow + r) * N + n] = acc[i][j][r] + bv[j];
      }
    }
  } else {
    const int which = n0 / CDIM;      // uniform per block (128 | 768)
    const int bb = m0 / SEQ;          // uniform per block (128 | 1024)
    const int tok0 = (m0 % SEQ) + wr * 64;
#pragma unroll
    for (int j = 0; j < 4; j++) {
      int ncol = (n0 % CDIM) + wc * 64 + j * 16;
      int hh = ncol / 64;             // uniform per fragment
      int d = (ncol % 64) + lr;
#pragma unroll
      for (int i = 0; i < 4; i++) {
        int tokb = tok0 + i * 16 + 4 * g;
        if (which == 2) {
          us4 pk;
#pragma unroll
          for (int r = 0; r < 4; r++) pk[r] = f2bf(acc[i][j][r] + bv[j]);
          *(us4*)(v_out + ((size_t)(bb * NHEAD + hh) * 64 + d) * SEQ + tokb) = pk;
        } else {
          unsigned short* dst = (which == 0) ? q_out : k_out;
#pragma unroll
          for (int r = 0; r < 4; r++)
            dst[((size_t)(bb * NHEAD + hh) * SEQ + tokb + r) * 64 + d] =
                f2bf(acc[i][j][r] + bv[j]);
        }
      }
    }
  }
}

// ---------------- fused flash attention ----------------
// grid: 768 blocks; XCD-grouped decode puts all 8 q-tiles of one (b,h) on one
// XCD (hw%8), heads interleaved across XCDs for balance. 4 waves/block.
// T14: next K/V tile + mask prefetched into registers during compute,
// committed to LDS via ds_write at the next loop head.
// No-max softmax: p = exp2(qk*scale_l2e + mask*l2e) directly (bounded logits,
// mathematically identical normalization; masked keys -> exp2(-1.4e9) = 0).
__global__ __launch_bounds__(256, 3)
void attn_kernel(const unsigned short* __restrict__ Qb,
                 const unsigned short* __restrict__ Kb,
                 const unsigned short* __restrict__ Vt,
                 const float* __restrict__ mask,
                 unsigned short* __restrict__ Ob) {
  __shared__ __align__(16) unsigned short Qs[128 * 64];
  __shared__ __align__(16) unsigned short Ks[128 * 64];
  __shared__ __align__(16) unsigned short Vs[64 * 128];
  __shared__ __align__(16) float smask[128];

  // bijective XCD-grouped decode
  const int hwb = blockIdx.x;
  const int x = hwb & 7;           // XCD (empirical hw%8 round-robin)
  const int i = hwb >> 3;          // [0,96)
  const int qt = i & 7;
  const int bh = (i >> 3) * 8 + x; // [0,96): all 8 qt of bh share XCD x
  const int h = bh % NHEAD, b = bh / NHEAD;

  const int t = threadIdx.x, w = t >> 6, l = t & 63;
  const int g = l >> 4, lr = l & 15;

  const unsigned short* Qg = Qb + (((size_t)b * NHEAD + h) * SEQ + qt * 128) * 64;
  const unsigned short* Kg = Kb + ((size_t)b * NHEAD + h) * SEQ * 64;
  const unsigned short* Vg = Vt + ((size_t)b * NHEAD + h) * 64 * SEQ;
  const float* mg = mask + (size_t)b * SEQ;

  // number of non-fully-masked key blocks (padding is a tail; lengths >= 512)
  int nkb = 8;
#pragma unroll
  for (int kb = 7; kb >= 4; kb--)
    if (mg[kb * 128] < -1e8f) nkb = kb;

  // ---- register prefetch machinery (same LDS layout as gload_lds path) ----
  bf16x8 kreg[4], vreg[4];
  float mreg;
  auto prefetch = [&](int kb) {
#pragma unroll
    for (int ii = 0; ii < 4; ii++) {
      int c = t + 256 * ii;
      int rk = c >> 3, sk = c & 7;
      kreg[ii] = *(const bf16x8*)(Kg + (size_t)(kb * 128 + rk) * 64 +
                                  ((sk ^ (rk & 7)) << 3));
      int rv = c >> 4, sv = c & 15;
      vreg[ii] = *(const bf16x8*)(Vg + (size_t)rv * SEQ + kb * 128 +
                                  ((sv ^ (rv & 7)) << 3));
    }
    mreg = (t < 128) ? mg[kb * 128 + t] * L2E : 0.f;
  };
  auto commit = [&]() {
#pragma unroll
    for (int ii = 0; ii < 4; ii++) {
      *(bf16x8*)(Ks + (t + 256 * ii) * 8) = kreg[ii];
      *(bf16x8*)(Vs + (t + 256 * ii) * 8) = vreg[ii];
    }
    if (t < 128) smask[t] = mreg;
  };

  // stage Q (XOR-swizzled rows) and prefetch tile 0 concurrently
#pragma unroll
  for (int ii = 0; ii < 4; ii++) {
    int c = t + 256 * ii;
    int row = c >> 3, sl = c & 7;
    gload_lds16(Qg + row * 64 + ((sl ^ (row & 7)) << 3), Qs + c * 8);
  }
  prefetch(0);
  __syncthreads();

  // hoist Q fragments (B-operand: col = query = lr, k = d)
  bf16x8 qfr[2][2];
#pragma unroll
  for (int qi = 0; qi < 2; qi++)
#pragma unroll
    for (int ks = 0; ks < 2; ks++) {
      int row = w * 32 + qi * 16 + lr;
      qfr[qi][ks] =
          *(const bf16x8*)(Qs + row * 64 + (((ks * 4 + g) ^ (lr & 7)) << 3));
    }

  float l_run[2] = {0.f, 0.f};
  f32x4 oacc[2][4];
#pragma unroll
  for (int qi = 0; qi < 2; qi++)
#pragma unroll
    for (int df = 0; df < 4; df++) oacc[qi][df] = f32x4{0.f, 0.f, 0.f, 0.f};

  for (int kb = 0; kb < nkb; kb++) {
    __syncthreads();  // previous compute's LDS reads done
    commit();         // reg -> LDS (loads completed during previous compute)
    __syncthreads();
    if (kb + 1 < nkb) prefetch(kb + 1);  // fly under this tile's compute

    // QK^T + exp2 + bf16-pack, interleaved per kf-pair (sacc peak = 16 regs)
    float bs[2] = {0.f, 0.f};
    bf16x8 pa[4][2];
#pragma unroll
    for (int kc = 0; kc < 4; kc++) {
      f32x4 s0[2], s1[2];
#pragma unroll
      for (int qi = 0; qi < 2; qi++) {
        s0[qi] = f32x4{0.f, 0.f, 0.f, 0.f};
        s1[qi] = f32x4{0.f, 0.f, 0.f, 0.f};
      }
#pragma unroll
      for (int ks = 0; ks < 2; ks++) {
        int row0 = (2 * kc) * 16 + lr;
        int row1 = (2 * kc + 1) * 16 + lr;
        int slot = ((ks * 4 + g) ^ (lr & 7)) << 3;
        bf16x8 a0 = *(const bf16x8*)(Ks + row0 * 64 + slot);
        bf16x8 a1 = *(const bf16x8*)(Ks + row1 * 64 + slot);
        s0[0] = mfma16(a0, qfr[0][ks], s0[0]);
        s0[1] = mfma16(a0, qfr[1][ks], s0[1]);
        s1[0] = mfma16(a1, qfr[0][ks], s1[0]);
        s1[1] = mfma16(a1, qfr[1][ks], s1[1]);
      }
      f32x4 mv0 = *(const f32x4*)(smask + (2 * kc) * 16 + 4 * g);
      f32x4 mv1 = *(const f32x4*)(smask + (2 * kc + 1) * 16 + 4 * g);
#pragma unroll
      for (int qi = 0; qi < 2; qi++) {
        union { bf16x8 v; unsigned short hh[8]; } u;
#pragma unroll
        for (int r = 0; r < 4; r++) {
          float p0 = __builtin_amdgcn_exp2f(fmaf(s0[qi][r], SCALE_L2E, mv0[r]));
          float p1 = __builtin_amdgcn_exp2f(fmaf(s1[qi][r], SCALE_L2E, mv1[r]));
          bs[qi] += p0 + p1;
          u.hh[r] = f2bf(p0);
          u.hh[4 + r] = f2bf(p1);
        }
        pa[kc][qi] = u.v;
      }
    }
    bs[0] += __shfl_xor(bs[0], 16);
    bs[0] += __shfl_xor(bs[0], 32);
    bs[1] += __shfl_xor(bs[1], 16);
    bs[1] += __shfl_xor(bs[1], 32);
    l_run[0] += bs[0];
    l_run[1] += bs[1];

    // PV: same k-slot bijection on both operands
    const int sw = (lr & 7) << 4;
#pragma unroll
    for (int kc = 0; kc < 4; kc++) {
#pragma unroll
      for (int df = 0; df < 4; df++) {
        const char* vp = (const char*)(Vs + (df * 16 + lr) * 128);
        bf16x4 lo = *(const bf16x4*)(vp + ((kc * 64 + 8 * g) ^ sw));
        bf16x4 hi = *(const bf16x4*)(vp + ((kc * 64 + 32 + 8 * g) ^ sw));
        bf16x8 vb = __builtin_shufflevector(lo, hi, 0, 1, 2, 3, 4, 5, 6, 7);
        oacc[0][df] = mfma16(pa[kc][0], vb, oacc[0][df]);
        oacc[1][df] = mfma16(pa[kc][1], vb, oacc[1][df]);
      }
    }
  }

  // epilogue: divide by l, write O as bf16 [B, tok, h*64 + d]
#pragma unroll
  for (int qi = 0; qi < 2; qi++) {
    float linv = 1.f / l_run[qi];
#pragma unroll
    for (int r = 0; r < 4; r++) {
      float li = __shfl(linv, 4 * g + r);
      int tok = qt * 128 + w * 32 + qi * 16 + 4 * g + r;
#pragma unroll
      for (int df = 0; df < 4; df++) {
        float val = oacc[qi][df][r] * li;
        Ob[((size_t)b * SEQ + tok) * CDIM + h * 64 + df * 16 + lr] = f2bf(val);
      }
    }
  }
}

// ---------------- launcher ----------------
extern "C" void kernel_launch(void* const* d_in, const int* in_sizes, int n_in,
                              void* d_out, int out_size, void* d_ws,
                              size_t ws_size, hipStream_t stream) {
  const float* x = (const float*)d_in[0];
  const float* mask = (const float*)d_in[1];
  const float* Wqkv = (const float*)d_in[2];
  const float* bqkv = (const float*)d_in[3];
  const float* Wproj = (const float*)d_in[4];
  const float* bproj = (const float*)d_in[5];
  float* out = (float*)d_out;

  char* ws = (char*)d_ws;
  size_t off = 0;
  auto take = [&](size_t bytes) {
    char* p = ws + off;
    off += (bytes + 255) & ~(size_t)255;
    return p;
  };
  unsigned short* xb = (unsigned short*)take((size_t)NB * SEQ * CDIM * 2);
  unsigned short* wqt = (unsigned short*)take((size_t)3 * CDIM * CDIM * 2);
  unsigned short* wpt = (unsigned short*)take((size_t)CDIM * CDIM * 2);
  unsigned short* Qb = (unsigned short*)take((size_t)NB * NHEAD * SEQ * 64 * 2);
  unsigned short* Kbf = (unsigned short*)take((size_t)NB * NHEAD * SEQ * 64 * 2);
  unsigned short* Vt = (unsigned short*)take((size_t)NB * NHEAD * SEQ * 64 * 2);
  unsigned short* Ob = (unsigned short*)take((size_t)NB * SEQ * CDIM * 2);

  int n8 = NB * SEQ * CDIM / 8;
  cvt_x_kernel<<<(n8 + 255) / 256, 256, 0, stream>>>(x, xb, n8);
  tconv_kernel<<<dim3(3 * CDIM / 32, CDIM / 32), 256, 0, stream>>>(Wqkv, wqt,
                                                                   CDIM, 3 * CDIM);
  tconv_kernel<<<dim3(CDIM / 32, CDIM / 32), 256, 0, stream>>>(Wproj, wpt, CDIM,
                                                               CDIM);
  gemm_bt_kernel<0><<<(NB * SEQ / 128) * (3 * CDIM / 128), 256, 0, stream>>>(
      xb, wqt, bqkv, Qb, Kbf, Vt, nullptr, NB * SEQ, 3 * CDIM, CDIM);
  attn_kernel<<<NB * NHEAD * 8, 256, 0, stream>>>(Qb, Kbf, Vt, mask, Ob);
  gemm_bt_kernel<1><<<(NB * SEQ / 128) * (CDIM / 128), 256, 0, stream>>>(
      Ob, wpt, bproj, nullptr, nullptr, nullptr, out, NB * SEQ, CDIM, CDIM);
}

// Round 4
// 198.970 us; speedup vs baseline: 1.1798x; 1.0653x over previous
//
#include <hip/hip_runtime.h>
#include <stdint.h>

#define NB 8
#define NHEAD 12
#define SEQ 1024
#define CDIM 768
#define HDIM 64

// (1/sqrt(64)) * log2(e)
#define SCALE_L2E 0.1803368801111244f
#define L2E 1.4426950408889634f

typedef __attribute__((ext_vector_type(8))) short bf16x8;
typedef __attribute__((ext_vector_type(4))) short bf16x4;
typedef __attribute__((ext_vector_type(4))) float f32x4;
typedef __attribute__((ext_vector_type(4))) unsigned short us4;

__device__ __forceinline__ void gload_lds16(const void* g, void* l) {
  __builtin_amdgcn_global_load_lds((const __attribute__((address_space(1))) void*)g,
                                   (__attribute__((address_space(3))) void*)l,
                                   16, 0, 0);
}

__device__ __forceinline__ unsigned short f2bf(float f) {
  __bf16 h = (__bf16)f;
  return __builtin_bit_cast(unsigned short, h);
}

__device__ __forceinline__ f32x4 mfma16(bf16x8 a, bf16x8 b, f32x4 c) {
  return __builtin_amdgcn_mfma_f32_16x16x32_bf16(a, b, c, 0, 0, 0);
}

// ---------------- conversion kernels ----------------

__global__ void cvt_x_kernel(const float* __restrict__ in,
                             unsigned short* __restrict__ out, int n8) {
  int i = blockIdx.x * blockDim.x + threadIdx.x;
  if (i >= n8) return;
  const float4* p = (const float4*)in;
  float4 a = p[2 * i], b = p[2 * i + 1];
  union { bf16x8 v; unsigned short h[8]; } u;
  u.h[0] = f2bf(a.x); u.h[1] = f2bf(a.y); u.h[2] = f2bf(a.z); u.h[3] = f2bf(a.w);
  u.h[4] = f2bf(b.x); u.h[5] = f2bf(b.y); u.h[6] = f2bf(b.z); u.h[7] = f2bf(b.w);
  ((bf16x8*)out)[i] = u.v;
}

// in [K][N] f32  ->  out [N][K] bf16   (grid: (N/32, K/32), 256 thr)
__global__ void tconv_kernel(const float* __restrict__ in,
                             unsigned short* __restrict__ out, int K, int N) {
  __shared__ float tile[32][33];
  int tx = threadIdx.x & 31, ty = threadIdx.x >> 5;
  int n0 = blockIdx.x * 32, k0 = blockIdx.y * 32;
#pragma unroll
  for (int i = 0; i < 4; i++)
    tile[ty + 8 * i][tx] = in[(size_t)(k0 + ty + 8 * i) * N + n0 + tx];
  __syncthreads();
#pragma unroll
  for (int i = 0; i < 4; i++)
    out[(size_t)(n0 + ty + 8 * i) * K + k0 + tx] = f2bf(tile[tx][ty + 8 * i]);
}

// ---------------- GEMM:  C[M][N] = A[M][K] * Bt[N][K]^T + bias ----------------
// 2-barrier structure, BK=64 (halves barrier-drains vs BK=32), XCD-chunked
// grid swizzle (each XCD owns a contiguous block range -> weight panel +
// A m-panel resident in that XCD's L2). Grid size must be a multiple of 8.
// EPI 0: scatter to Q [B,H,N,D], K [B,H,N,D], V^T [B,H,D,N]  (bf16)
// EPI 1: f32 out [M][N]
template <int EPI>
__global__ __launch_bounds__(256, 4)
void gemm_bt_kernel(const unsigned short* __restrict__ A,
                    const unsigned short* __restrict__ Bt,
                    const float* __restrict__ bias,
                    unsigned short* __restrict__ q_out,
                    unsigned short* __restrict__ k_out,
                    unsigned short* __restrict__ v_out,
                    float* __restrict__ f_out,
                    int M, int N, int K) {
  __shared__ __align__(16) unsigned short As[128 * 64];
  __shared__ __align__(16) unsigned short Bs[128 * 64];
  const int t = threadIdx.x;
  const int w = t >> 6, l = t & 63;
  const int g = l >> 4, lr = l & 15;
  const int wr = w >> 1, wc = w & 1;
  const int nTN = N >> 7;
  // XCD-chunked bijective swizzle (gridDim.x % 8 == 0)
  const int bpx = gridDim.x >> 3;
  const int orig = (blockIdx.x & 7) * bpx + (blockIdx.x >> 3);
  const int bm = orig / nTN, bn = orig % nTN;
  const int m0 = bm << 7, n0 = bn << 7;

  f32x4 acc[4][4];
#pragma unroll
  for (int i = 0; i < 4; i++)
#pragma unroll
    for (int j = 0; j < 4; j++) acc[i][j] = f32x4{0.f, 0.f, 0.f, 0.f};

  // staging: 4 chunks/thread/tile; chunk c = t + 256*i:
  // row = c>>3, slot = c&7, source k-chunk = slot ^ (row&7)  (involution)
  const unsigned short* aP[4];
  const unsigned short* bP[4];
  unsigned short* lA[4];
  unsigned short* lB[4];
#pragma unroll
  for (int i = 0; i < 4; i++) {
    int c = t + 256 * i;
    int r = c >> 3, s = c & 7;
    int ko = (s ^ (r & 7)) * 8;
    aP[i] = A + (size_t)(m0 + r) * K + ko;
    bP[i] = Bt + (size_t)(n0 + r) * K + ko;
    lA[i] = As + c * 8;
    lB[i] = Bs + c * 8;
  }

  for (int kk = 0; kk < K; kk += 64) {
#pragma unroll
    for (int i = 0; i < 4; i++) {
      gload_lds16(aP[i] + kk, lA[i]);
      gload_lds16(bP[i] + kk, lB[i]);
    }
    __syncthreads();  // drains vmcnt -> staged data visible
#pragma unroll
    for (int ks = 0; ks < 2; ks++) {
      const int slot = ((ks * 4 + g) ^ (lr & 7)) << 3;
      bf16x8 af[4];
#pragma unroll
      for (int i = 0; i < 4; i++) {
        int row = wr * 64 + i * 16 + lr;  // row&7 == lr&7
        af[i] = *(const bf16x8*)(As + row * 64 + slot);
      }
#pragma unroll
      for (int j = 0; j < 4; j++) {
        int row = wc * 64 + j * 16 + lr;
        bf16x8 bfr = *(const bf16x8*)(Bs + row * 64 + slot);
#pragma unroll
        for (int i = 0; i < 4; i++) acc[i][j] = mfma16(af[i], bfr, acc[i][j]);
      }
    }
    __syncthreads();  // compute done before next overwrite
  }

  float bv[4];
#pragma unroll
  for (int j = 0; j < 4; j++) bv[j] = bias[n0 + wc * 64 + j * 16 + lr];

  if (EPI == 1) {
#pragma unroll
    for (int i = 0; i < 4; i++) {
      int mrow = m0 + wr * 64 + i * 16 + 4 * g;
#pragma unroll
      for (int j = 0; j < 4; j++) {
        int n = n0 + wc * 64 + j * 16 + lr;
#pragma unroll
        for (int r = 0; r < 4; r++)
          f_out[(size_t)(mrow + r) * N + n] = acc[i][j][r] + bv[j];
      }
    }
  } else {
    const int which = n0 / CDIM;      // uniform per block (128 | 768)
    const int bb = m0 / SEQ;          // uniform per block (128 | 1024)
    const int tok0 = (m0 % SEQ) + wr * 64;
#pragma unroll
    for (int j = 0; j < 4; j++) {
      int ncol = (n0 % CDIM) + wc * 64 + j * 16;
      int hh = ncol / 64;             // uniform per fragment
      int d = (ncol % 64) + lr;
#pragma unroll
      for (int i = 0; i < 4; i++) {
        int tokb = tok0 + i * 16 + 4 * g;
        if (which == 2) {
          us4 pk;
#pragma unroll
          for (int r = 0; r < 4; r++) pk[r] = f2bf(acc[i][j][r] + bv[j]);
          *(us4*)(v_out + ((size_t)(bb * NHEAD + hh) * 64 + d) * SEQ + tokb) = pk;
        } else {
          unsigned short* dst = (which == 0) ? q_out : k_out;
#pragma unroll
          for (int r = 0; r < 4; r++)
            dst[((size_t)(bb * NHEAD + hh) * SEQ + tokb + r) * 64 + d] =
                f2bf(acc[i][j][r] + bv[j]);
        }
      }
    }
  }
}

// ---------------- fused flash attention ----------------
// grid: 768 blocks; XCD-grouped decode puts all 8 q-tiles of one (b,h) on one
// XCD (hw%8), heads interleaved across XCDs for balance. 4 waves/block.
// T14: next K/V tile + mask prefetched into registers during compute,
// committed to LDS via ds_write at the next loop head.
// No-max softmax: p = exp2(qk*scale_l2e + mask*l2e) directly (bounded logits,
// mathematically identical normalization; masked keys -> exp2(-1.4e9) = 0).
__global__ __launch_bounds__(256, 3)
void attn_kernel(const unsigned short* __restrict__ Qb,
                 const unsigned short* __restrict__ Kb,
                 const unsigned short* __restrict__ Vt,
                 const float* __restrict__ mask,
                 unsigned short* __restrict__ Ob) {
  __shared__ __align__(16) unsigned short Qs[128 * 64];
  __shared__ __align__(16) unsigned short Ks[128 * 64];
  __shared__ __align__(16) unsigned short Vs[64 * 128];
  __shared__ __align__(16) float smask[128];

  // bijective XCD-grouped decode
  const int hwb = blockIdx.x;
  const int x = hwb & 7;           // XCD (empirical hw%8 round-robin)
  const int i = hwb >> 3;          // [0,96)
  const int qt = i & 7;
  const int bh = (i >> 3) * 8 + x; // [0,96): all 8 qt of bh share XCD x
  const int h = bh % NHEAD, b = bh / NHEAD;

  const int t = threadIdx.x, w = t >> 6, l = t & 63;
  const int g = l >> 4, lr = l & 15;

  const unsigned short* Qg = Qb + (((size_t)b * NHEAD + h) * SEQ + qt * 128) * 64;
  const unsigned short* Kg = Kb + ((size_t)b * NHEAD + h) * SEQ * 64;
  const unsigned short* Vg = Vt + ((size_t)b * NHEAD + h) * 64 * SEQ;
  const float* mg = mask + (size_t)b * SEQ;

  // number of non-fully-masked key blocks (padding is a tail; lengths >= 512)
  int nkb = 8;
#pragma unroll
  for (int kb = 7; kb >= 4; kb--)
    if (mg[kb * 128] < -1e8f) nkb = kb;

  // ---- register prefetch machinery (same LDS layout as gload_lds path) ----
  bf16x8 kreg[4], vreg[4];
  float mreg;
  auto prefetch = [&](int kb) {
#pragma unroll
    for (int ii = 0; ii < 4; ii++) {
      int c = t + 256 * ii;
      int rk = c >> 3, sk = c & 7;
      kreg[ii] = *(const bf16x8*)(Kg + (size_t)(kb * 128 + rk) * 64 +
                                  ((sk ^ (rk & 7)) << 3));
      int rv = c >> 4, sv = c & 15;
      vreg[ii] = *(const bf16x8*)(Vg + (size_t)rv * SEQ + kb * 128 +
                                  ((sv ^ (rv & 7)) << 3));
    }
    mreg = (t < 128) ? mg[kb * 128 + t] * L2E : 0.f;
  };
  auto commit = [&]() {
#pragma unroll
    for (int ii = 0; ii < 4; ii++) {
      *(bf16x8*)(Ks + (t + 256 * ii) * 8) = kreg[ii];
      *(bf16x8*)(Vs + (t + 256 * ii) * 8) = vreg[ii];
    }
    if (t < 128) smask[t] = mreg;
  };

  // stage Q (XOR-swizzled rows) and prefetch tile 0 concurrently
#pragma unroll
  for (int ii = 0; ii < 4; ii++) {
    int c = t + 256 * ii;
    int row = c >> 3, sl = c & 7;
    gload_lds16(Qg + row * 64 + ((sl ^ (row & 7)) << 3), Qs + c * 8);
  }
  prefetch(0);
  __syncthreads();

  // hoist Q fragments (B-operand: col = query = lr, k = d)
  bf16x8 qfr[2][2];
#pragma unroll
  for (int qi = 0; qi < 2; qi++)
#pragma unroll
    for (int ks = 0; ks < 2; ks++) {
      int row = w * 32 + qi * 16 + lr;
      qfr[qi][ks] =
          *(const bf16x8*)(Qs + row * 64 + (((ks * 4 + g) ^ (lr & 7)) << 3));
    }

  float l_run[2] = {0.f, 0.f};
  f32x4 oacc[2][4];
#pragma unroll
  for (int qi = 0; qi < 2; qi++)
#pragma unroll
    for (int df = 0; df < 4; df++) oacc[qi][df] = f32x4{0.f, 0.f, 0.f, 0.f};

  for (int kb = 0; kb < nkb; kb++) {
    __syncthreads();  // previous compute's LDS reads done
    commit();         // reg -> LDS (loads completed during previous compute)
    __syncthreads();
    if (kb + 1 < nkb) prefetch(kb + 1);  // fly under this tile's compute

    // QK^T + exp2 + bf16-pack, interleaved per kf-pair (sacc peak = 16 regs)
    float bs[2] = {0.f, 0.f};
    bf16x8 pa[4][2];
#pragma unroll
    for (int kc = 0; kc < 4; kc++) {
      f32x4 s0[2], s1[2];
#pragma unroll
      for (int qi = 0; qi < 2; qi++) {
        s0[qi] = f32x4{0.f, 0.f, 0.f, 0.f};
        s1[qi] = f32x4{0.f, 0.f, 0.f, 0.f};
      }
#pragma unroll
      for (int ks = 0; ks < 2; ks++) {
        int row0 = (2 * kc) * 16 + lr;
        int row1 = (2 * kc + 1) * 16 + lr;
        int slot = ((ks * 4 + g) ^ (lr & 7)) << 3;
        bf16x8 a0 = *(const bf16x8*)(Ks + row0 * 64 + slot);
        bf16x8 a1 = *(const bf16x8*)(Ks + row1 * 64 + slot);
        s0[0] = mfma16(a0, qfr[0][ks], s0[0]);
        s0[1] = mfma16(a0, qfr[1][ks], s0[1]);
        s1[0] = mfma16(a1, qfr[0][ks], s1[0]);
        s1[1] = mfma16(a1, qfr[1][ks], s1[1]);
      }
      f32x4 mv0 = *(const f32x4*)(smask + (2 * kc) * 16 + 4 * g);
      f32x4 mv1 = *(const f32x4*)(smask + (2 * kc + 1) * 16 + 4 * g);
#pragma unroll
      for (int qi = 0; qi < 2; qi++) {
        union { bf16x8 v; unsigned short hh[8]; } u;
#pragma unroll
        for (int r = 0; r < 4; r++) {
          float p0 = __builtin_amdgcn_exp2f(fmaf(s0[qi][r], SCALE_L2E, mv0[r]));
          float p1 = __builtin_amdgcn_exp2f(fmaf(s1[qi][r], SCALE_L2E, mv1[r]));
          bs[qi] += p0 + p1;
          u.hh[r] = f2bf(p0);
          u.hh[4 + r] = f2bf(p1);
        }
        pa[kc][qi] = u.v;
      }
    }
    bs[0] += __shfl_xor(bs[0], 16);
    bs[0] += __shfl_xor(bs[0], 32);
    bs[1] += __shfl_xor(bs[1], 16);
    bs[1] += __shfl_xor(bs[1], 32);
    l_run[0] += bs[0];
    l_run[1] += bs[1];

    // PV: same k-slot bijection on both operands
    const int sw = (lr & 7) << 4;
#pragma unroll
    for (int kc = 0; kc < 4; kc++) {
#pragma unroll
      for (int df = 0; df < 4; df++) {
        const char* vp = (const char*)(Vs + (df * 16 + lr) * 128);
        bf16x4 lo = *(const bf16x4*)(vp + ((kc * 64 + 8 * g) ^ sw));
        bf16x4 hi = *(const bf16x4*)(vp + ((kc * 64 + 32 + 8 * g) ^ sw));
        bf16x8 vb = __builtin_shufflevector(lo, hi, 0, 1, 2, 3, 4, 5, 6, 7);
        oacc[0][df] = mfma16(pa[kc][0], vb, oacc[0][df]);
        oacc[1][df] = mfma16(pa[kc][1], vb, oacc[1][df]);
      }
    }
  }

  // epilogue: divide by l, write O as bf16 [B, tok, h*64 + d]
#pragma unroll
  for (int qi = 0; qi < 2; qi++) {
    float linv = 1.f / l_run[qi];
#pragma unroll
    for (int r = 0; r < 4; r++) {
      float li = __shfl(linv, 4 * g + r);
      int tok = qt * 128 + w * 32 + qi * 16 + 4 * g + r;
#pragma unroll
      for (int df = 0; df < 4; df++) {
        float val = oacc[qi][df][r] * li;
        Ob[((size_t)b * SEQ + tok) * CDIM + h * 64 + df * 16 + lr] = f2bf(val);
      }
    }
  }
}

// ---------------- launcher ----------------
extern "C" void kernel_launch(void* const* d_in, const int* in_sizes, int n_in,
                              void* d_out, int out_size, void* d_ws,
                              size_t ws_size, hipStream_t stream) {
  const float* x = (const float*)d_in[0];
  const float* mask = (const float*)d_in[1];
  const float* Wqkv = (const float*)d_in[2];
  const float* bqkv = (const float*)d_in[3];
  const float* Wproj = (const float*)d_in[4];
  const float* bproj = (const float*)d_in[5];
  float* out = (float*)d_out;

  char* ws = (char*)d_ws;
  size_t off = 0;
  auto take = [&](size_t bytes) {
    char* p = ws + off;
    off += (bytes + 255) & ~(size_t)255;
    return p;
  };
  unsigned short* xb = (unsigned short*)take((size_t)NB * SEQ * CDIM * 2);
  unsigned short* wqt = (unsigned short*)take((size_t)3 * CDIM * CDIM * 2);
  unsigned short* wpt = (unsigned short*)take((size_t)CDIM * CDIM * 2);
  unsigned short* Qb = (unsigned short*)take((size_t)NB * NHEAD * SEQ * 64 * 2);
  unsigned short* Kbf = (unsigned short*)take((size_t)NB * NHEAD * SEQ * 64 * 2);
  unsigned short* Vt = (unsigned short*)take((size_t)NB * NHEAD * SEQ * 64 * 2);
  unsigned short* Ob = (unsigned short*)take((size_t)NB * SEQ * CDIM * 2);

  int n8 = NB * SEQ * CDIM / 8;
  cvt_x_kernel<<<(n8 + 255) / 256, 256, 0, stream>>>(x, xb, n8);
  tconv_kernel<<<dim3(3 * CDIM / 32, CDIM / 32), 256, 0, stream>>>(Wqkv, wqt,
                                                                   CDIM, 3 * CDIM);
  tconv_kernel<<<dim3(CDIM / 32, CDIM / 32), 256, 0, stream>>>(Wproj, wpt, CDIM,
                                                               CDIM);
  gemm_bt_kernel<0><<<(NB * SEQ / 128) * (3 * CDIM / 128), 256, 0, stream>>>(
      xb, wqt, bqkv, Qb, Kbf, Vt, nullptr, NB * SEQ, 3 * CDIM, CDIM);
  attn_kernel<<<NB * NHEAD * 8, 256, 0, stream>>>(Qb, Kbf, Vt, mask, Ob);
  gemm_bt_kernel<1><<<(NB * SEQ / 128) * (CDIM / 128), 256, 0, stream>>>(
      Ob, wpt, bproj, nullptr, nullptr, nullptr, out, NB * SEQ, CDIM, CDIM);
}